// Round 11
// baseline (145.359 us; speedup 1.0000x reference)
//
#include <hip/hip_runtime.h>
#include <hip/hip_fp16.h>
#include <float.h>

#define NN 100000
#define NE 1600000
#define NB 391        // buckets of 256 nodes (dst >> 8)
#define NBLK 512      // hist/partition blocks
#define CHUNK 3125    // NE / NBLK
#define TOT (NB * NBLK)              // 200192 hist entries
#define SCAN_B2 ((TOT + 255) / 256)  // 782
#define NODE1_B 391   // node1 blocks: 391*256 = 100096 rows
#define MAXB 12288    // LDS-staged bucket capacity (mean 4092, sigma 64 -> safe)

// ---------- edge loading (int32 vs int64, detected per-block) ----------

__device__ __forceinline__ void load_edge(const int* __restrict__ ei, int is64,
                                          int idx, int& s, int& d) {
    if (is64) {
        const long long* e64 = (const long long*)ei;
        s = (int)e64[idx]; d = (int)e64[NE + idx];
    } else {
        s = ei[idx]; d = ei[NE + idx];
    }
}

__device__ __forceinline__ int load_dst(const int* __restrict__ ei, int is64, int idx) {
    if (is64) return (int)((const long long*)ei)[NE + idx];
    return ei[NE + idx];
}

// first 64 words: odd words are all-zero iff int64 (values < 2^31).
__device__ __forceinline__ int detect64(const int* __restrict__ ei, int t, int* s_flag) {
    if (t < 64) {
        unsigned w = ((const unsigned*)ei)[t];
        unsigned long long m = __ballot((t & 1) && w != 0);
        if (t == 0) *s_flag = (m == 0) ? 1 : 0;
    }
    __syncthreads();
    return *s_flag;
}

// ---------- fused: histogram + layer-1 node transform ----------
// blocks [0, NBLK): per-(block,bucket) histogram of dst (LDS counters).
// blocks [NBLK, NBLK+NODE1_B): node1, lane = row, NO LDS:
//   x row streamed per-lane as float4; W rows via wave-uniform loads (s_load);
//   32 fp32 accumulators; writes per-head fp16 h1a/h1b + per-head alphas.

__global__ __launch_bounds__(256) void k_hist_node1(
    const int* __restrict__ ei, int* __restrict__ hist_g,
    const float* __restrict__ x, const float* __restrict__ W1,
    const float* __restrict__ att_s, const float* __restrict__ att_d,
    unsigned* __restrict__ h1a, unsigned* __restrict__ h1b,
    float* __restrict__ as1h0, float* __restrict__ as1h1,
    float* __restrict__ ad1h0, float* __restrict__ ad1h1) {
    __shared__ int h[NB];
    __shared__ int s_flag;
    int t = threadIdx.x;
    if (blockIdx.x < NBLK) {
        // ---- histogram ----
        for (int i = t; i < NB; i += 256) h[i] = 0;
        int is64 = detect64(ei, t, &s_flag);   // barrier covers h zeroing
        int base = blockIdx.x * CHUNK;
        for (int k = t; k < CHUNK; k += 256) {
            int d = load_dst(ei, is64, base + k);
            atomicAdd(&h[d >> 8], 1);
        }
        __syncthreads();
        for (int i = t; i < NB; i += 256) hist_g[i * NBLK + blockIdx.x] = h[i];
    } else {
        // ---- node1 ----
        int lane = t & 63;
        int row = (blockIdx.x - NBLK) * 256 + (t & 192) + lane;  // 4 waves x 64 rows
        int r = row < NN ? row : NN - 1;
        const float4* xr = (const float4*)(x + (size_t)r * 128);
        float acc[32];
        #pragma unroll
        for (int j = 0; j < 32; ++j) acc[j] = 0.f;
        for (int k4 = 0; k4 < 32; ++k4) {       // 4 k-values per iter
            float4 a = xr[k4];
            const float* Wr = W1 + k4 * 128;    // wave-uniform -> scalar loads
            #pragma unroll
            for (int c = 0; c < 4; ++c) {
                float xs = c == 0 ? a.x : c == 1 ? a.y : c == 2 ? a.z : a.w;
                #pragma unroll
                for (int j = 0; j < 32; ++j)
                    acc[j] = fmaf(xs, Wr[c * 32 + j], acc[j]);
            }
        }
        // alphas (att vectors wave-uniform -> scalar loads)
        float s0 = 0.f, s1 = 0.f, d0 = 0.f, d1 = 0.f;
        #pragma unroll
        for (int j = 0; j < 16; ++j) {
            s0 = fmaf(acc[j], att_s[j], s0);
            d0 = fmaf(acc[j], att_d[j], d0);
            s1 = fmaf(acc[16 + j], att_s[16 + j], s1);
            d1 = fmaf(acc[16 + j], att_d[16 + j], d1);
        }
        if (row < NN) {
            unsigned pk[16];
            #pragma unroll
            for (int q = 0; q < 16; ++q) {
                __half2 hv = __floats2half2_rn(acc[2 * q], acc[2 * q + 1]);
                pk[q] = *(unsigned*)&hv;
            }
            uint4* ha = (uint4*)h1a;
            ha[row * 2]     = make_uint4(pk[0], pk[1], pk[2], pk[3]);
            ha[row * 2 + 1] = make_uint4(pk[4], pk[5], pk[6], pk[7]);
            uint4* hb = (uint4*)h1b;
            hb[row * 2]     = make_uint4(pk[8], pk[9], pk[10], pk[11]);
            hb[row * 2 + 1] = make_uint4(pk[12], pk[13], pk[14], pk[15]);
            as1h0[row] = s0; as1h1[row] = s1;
            ad1h0[row] = d0; ad1h1[row] = d1;
        }
    }
}

// ---------- scan phase 1: per-block sums of 256-entry hist chunks ----------

__global__ __launch_bounds__(256) void k_scan1(const int* __restrict__ hist_g,
                                               int* __restrict__ bsum) {
    __shared__ int part[4];
    int t = threadIdx.x;
    int i = blockIdx.x * 256 + t;
    int v = (i < TOT) ? hist_g[i] : 0;
    #pragma unroll
    for (int off = 32; off; off >>= 1) v += __shfl_xor(v, off);
    if ((t & 63) == 0) part[t >> 6] = v;
    __syncthreads();
    if (t == 0) bsum[blockIdx.x] = part[0] + part[1] + part[2] + part[3];
}

// ---------- scan phase 2+3 fused ----------

__global__ __launch_bounds__(256) void k_scan3(const int* __restrict__ hist_g,
                                               const int* __restrict__ bsum,
                                               int* __restrict__ hist_s,
                                               int* __restrict__ bbase) {
    __shared__ int red[4];
    __shared__ int s[256];
    int t = threadIdx.x, b = blockIdx.x;
    int partial = 0;
    for (int i = t; i < b; i += 256) partial += bsum[i];   // L2-hot
    #pragma unroll
    for (int off = 32; off; off >>= 1) partial += __shfl_xor(partial, off);
    if ((t & 63) == 0) red[t >> 6] = partial;
    int i = b * 256 + t;
    int v = (i < TOT) ? hist_g[i] : 0;
    s[t] = v;
    __syncthreads();
    int boff = red[0] + red[1] + red[2] + red[3];
    for (int off = 1; off < 256; off <<= 1) {
        int u = (t >= off) ? s[t - off] : 0;
        __syncthreads();
        s[t] += u;
        __syncthreads();
    }
    if (i < TOT) {
        int e = boff + s[t] - v;
        hist_s[i] = e;
        if ((i & (NBLK - 1)) == 0) bbase[i / NBLK] = e;
    }
    if (b == 0 && t == 0) bbase[NB] = NE;
}

// ---------- partition: place packed (src<<8 | dst&255) ----------

__global__ __launch_bounds__(512) void k_part(const int* __restrict__ ei,
                                              const int* __restrict__ hist_s,
                                              unsigned* __restrict__ pairs) {
    __shared__ int cur[NB];
    __shared__ int s_flag;
    int t = threadIdx.x;
    for (int i = t; i < NB; i += 512) cur[i] = hist_s[i * NBLK + blockIdx.x];
    int is64 = detect64(ei, t, &s_flag);
    int base = blockIdx.x * CHUNK;
    for (int k = t; k < CHUNK; k += 512) {
        int s, d; load_edge(ei, is64, base + k, s, d);
        int p = atomicAdd(&cur[d >> 8], 1);
        pairs[p] = ((unsigned)s << 8) | (unsigned)(d & 255);
    }
}

// ---------- per-bucket local CSR build (LDS-staged; srcs aliases pairs) ----------

__global__ __launch_bounds__(256) void k_csr(const unsigned* __restrict__ pairs,
                                             const int* __restrict__ bbase,
                                             int* __restrict__ offs,
                                             int* __restrict__ srcs) {
    __shared__ unsigned plds[MAXB];
    __shared__ int cnt_l[256];
    __shared__ int scan_l[256];
    int b = blockIdx.x, t = threadIdx.x;
    int beg = bbase[b], end = bbase[b + 1];
    int m = end - beg;
    if (m > MAXB) m = MAXB;
    for (int k = t; k < m; k += 256) plds[k] = pairs[beg + k];
    cnt_l[t] = 0;
    __syncthreads();
    for (int k = t; k < m; k += 256) atomicAdd(&cnt_l[plds[k] & 255], 1);
    __syncthreads();
    int v = cnt_l[t];
    scan_l[t] = v;
    __syncthreads();
    for (int off = 1; off < 256; off <<= 1) {
        int u = (t >= off) ? scan_l[t - off] : 0;
        __syncthreads();
        scan_l[t] += u;
        __syncthreads();
    }
    int lexcl = scan_l[t] - v;
    int node = (b << 8) + t;
    if (node < NN) offs[node] = beg + lexcl;
    if (b == 0 && t == 0) offs[NN] = NE;
    cnt_l[t] = lexcl;
    __syncthreads();
    for (int k = t; k < m; k += 256) {
        unsigned e = plds[k];
        int p = atomicAdd(&cnt_l[e & 255], 1);
        srcs[beg + p] = (int)(e >> 8);
    }
}

// ---------- layer 1 aggregate, one pass per head ----------
// One wave per dst node: 16 edge-groups x 4 lanes; each lane handles 4 feats
// (uint2 = 2x half2) -> 16 edges per loop iteration. Per-head gather table is
// 3.2 MB -> fits per-XCD L2. Pass 0 stores relu'd o1-head0 (fp16); pass 1
// combines both heads through W2 -> hx = {h2_0, h2_1, as2, ad2} fp16.

template <int H>
__global__ __launch_bounds__(256) void k_agg1h(
    const int* __restrict__ offs, const int* __restrict__ srcs,
    const float* __restrict__ as1h, const float* __restrict__ ad1h,
    const uint2* __restrict__ h1H, const float* __restrict__ b1,
    const float* __restrict__ W2, const float* __restrict__ as2w,
    const float* __restrict__ ad2w, uint2* __restrict__ o1a,
    uint2* __restrict__ hx) {
    int n = (blockIdx.x * blockDim.x + threadIdx.x) >> 6;
    if (n >= NN) return;
    int lane = threadIdx.x & 63;
    int eg = lane >> 2;          // edge group 0..15
    int j4 = lane & 3;           // feature quad: feats {4*j4 .. 4*j4+3} of this head
    int beg = offs[n];
    int deg = offs[n + 1] - beg;           // +1 virtual self-loop
    int tot = deg + 1;
    float adh = ad1h[n];
    float ac0 = 0.f, ac1 = 0.f, ac2 = 0.f, ac3 = 0.f, dsum = 0.f;
    int k = eg;
    int s0 = (k < tot) ? ((k < deg) ? srcs[beg + k] : n) : 0;
    float a0 = as1h[s0];
    uint2 v0 = h1H[s0 * 4 + j4];
    for (; k < tot; k += 16) {
        int kn = k + 16;
        int s1 = (kn < tot) ? ((kn < deg) ? srcs[beg + kn] : n) : 0;
        float a1 = as1h[s1];
        uint2 v1 = h1H[s1 * 4 + j4];
        float e = a0 + adh;
        e = fmaxf(e, 0.2f * e);            // leaky_relu
        float p = __expf(e);
        float2 fa = __half22float2(*(__half2*)&v0.x);
        float2 fb = __half22float2(*(__half2*)&v0.y);
        ac0 = fmaf(p, fa.x, ac0);
        ac1 = fmaf(p, fa.y, ac1);
        ac2 = fmaf(p, fb.x, ac2);
        ac3 = fmaf(p, fb.y, ac3);
        dsum += p;                          // per-j4 column; each edge once
        s0 = s1; a0 = a1; v0 = v1;
    }
    // reduce across the 16 edge groups (lane bits 2..5)
    #pragma unroll
    for (int off = 4; off <= 32; off <<= 1) {
        ac0 += __shfl_xor(ac0, off);
        ac1 += __shfl_xor(ac1, off);
        ac2 += __shfl_xor(ac2, off);
        ac3 += __shfl_xor(ac3, off);
        dsum += __shfl_xor(dsum, off);
    }
    float inv = 1.f / (dsum + 1e-16f);
    float4 bb = ((const float4*)b1)[H * 4 + j4];
    float r0 = fmaxf(ac0 * inv + bb.x, 0.f);
    float r1 = fmaxf(ac1 * inv + bb.y, 0.f);
    float r2 = fmaxf(ac2 * inv + bb.z, 0.f);
    float r3 = fmaxf(ac3 * inv + bb.w, 0.f);
    if (H == 0) {
        if (eg == 0) {
            __half2 lo = __floats2half2_rn(r0, r1);
            __half2 hi = __floats2half2_rn(r2, r3);
            uint2 pk;
            pk.x = *(unsigned*)&lo;
            pk.y = *(unsigned*)&hi;
            o1a[n * 4 + j4] = pk;
        }
    } else {
        uint2 pv = o1a[n * 4 + j4];
        float2 p01 = __half22float2(*(__half2*)&pv.x);
        float2 p23 = __half22float2(*(__half2*)&pv.y);
        float4 wA = ((const float4*)W2)[2 * j4];       // head0 rows 4j4,4j4+1
        float4 wB = ((const float4*)W2)[2 * j4 + 1];   // head0 rows 4j4+2,4j4+3
        float4 wC = ((const float4*)W2)[8 + 2 * j4];   // head1 rows 16+4j4,..
        float4 wD = ((const float4*)W2)[9 + 2 * j4];
        float c0 = p01.x * wA.x + p01.y * wA.z + p23.x * wB.x + p23.y * wB.z
                 + r0 * wC.x + r1 * wC.z + r2 * wD.x + r3 * wD.z;
        float c1 = p01.x * wA.y + p01.y * wA.w + p23.x * wB.y + p23.y * wB.w
                 + r0 * wC.y + r1 * wC.w + r2 * wD.y + r3 * wD.w;
        c0 += __shfl_xor(c0, 1); c0 += __shfl_xor(c0, 2);
        c1 += __shfl_xor(c1, 1); c1 += __shfl_xor(c1, 2);
        if (lane == 0) {
            float a_s = c0 * as2w[0] + c1 * as2w[1];
            float a_d = c0 * ad2w[0] + c1 * ad2w[1];
            __half2 lo = __floats2half2_rn(c0, c1);
            __half2 hi = __floats2half2_rn(a_s, a_d);
            uint2 pk;
            pk.x = *(unsigned*)&lo;
            pk.y = *(unsigned*)&hi;
            hx[n] = pk;
        }
    }
}

// ---------- layer 2 aggregate: 16 lanes per dst node, value-prefetched ----------

__global__ __launch_bounds__(256) void k_agg2(
    const int* __restrict__ offs, const int* __restrict__ srcs,
    const uint2* __restrict__ hx, const float* __restrict__ b2,
    float* __restrict__ out) {
    int n = (blockIdx.x * blockDim.x + threadIdx.x) >> 4;
    if (n >= NN) return;
    int lane = threadIdx.x & 15;
    int beg = offs[n];
    int deg = offs[n + 1] - beg;
    uint2 mynode = hx[n];
    __half2 myhi = *(__half2*)&mynode.y;
    float adv = __high2float(myhi);
    float dsum = 0.f, s0acc = 0.f, s1acc = 0.f;
    int k = lane;
    int s0 = (k <= deg) ? ((k < deg) ? srcs[beg + k] : n) : 0;
    uint2 r0 = hx[s0];
    for (; k <= deg; k += 16) {
        int kn = k + 16;
        int s1 = (kn <= deg) ? ((kn < deg) ? srcs[beg + kn] : n) : 0;
        uint2 r1 = hx[s1];
        __half2 lo = *(__half2*)&r0.x;   // {h2_0, h2_1}
        __half2 hi = *(__half2*)&r0.y;   // {as2, ad2}
        float e = __low2float(hi) + adv;
        e = fmaxf(e, 0.2f * e);
        float p = __expf(e);
        dsum += p;
        s0acc = fmaf(p, __low2float(lo), s0acc);
        s1acc = fmaf(p, __high2float(lo), s1acc);
        r0 = r1;
    }
    #pragma unroll
    for (int off = 8; off; off >>= 1) {
        dsum  += __shfl_xor(dsum, off, 16);
        s0acc += __shfl_xor(s0acc, off, 16);
        s1acc += __shfl_xor(s1acc, off, 16);
    }
    if (lane == 0) {
        float inv = 1.f / (dsum + 1e-16f);
        out[n * 2]     = s0acc * inv + b2[0];
        out[n * 2 + 1] = s1acc * inv + b2[1];
    }
}

// ---------- launch ----------

extern "C" void kernel_launch(void* const* d_in, const int* in_sizes, int n_in,
                              void* d_out, int out_size, void* d_ws, size_t ws_size,
                              hipStream_t stream) {
    const float* x    = (const float*)d_in[0];
    const int*   ei   = (const int*)d_in[1];
    const float* W1   = (const float*)d_in[2];
    const float* as1w = (const float*)d_in[3];
    const float* ad1w = (const float*)d_in[4];
    const float* b1   = (const float*)d_in[5];
    const float* W2   = (const float*)d_in[6];
    const float* as2w = (const float*)d_in[7];
    const float* ad2w = (const float*)d_in[8];
    const float* b2   = (const float*)d_in[9];
    float* out = (float*)d_out;

    float* ws = (float*)d_ws;
    unsigned* h1a = (unsigned*)ws; ws += 8 * NN;   // head0 fp16 [n][16] = 3.2 MB
    unsigned* h1b = (unsigned*)ws; ws += 8 * NN;   // head1 fp16
    float* as1h0 = ws; ws += NN;
    float* as1h1 = ws; ws += NN;
    float* ad1h0 = ws; ws += NN;
    float* ad1h1 = ws; ws += NN;
    uint2* o1a = (uint2*)ws; ws += 8 * NN;         // relu'd o1 head0 fp16: NN x 4 uint2 = 3.2 MB
    uint2* hx  = (uint2*)ws; ws += 2 * NN;
    int* offs   = (int*)ws; ws += NN + 1;
    int* srcs   = (int*)ws; ws += NE;
    int* hist_g = (int*)ws; ws += TOT;
    int* hist_s = (int*)ws; ws += TOT;
    int* bsum   = (int*)ws; ws += SCAN_B2;
    int* bbase  = (int*)ws; ws += NB + 1;
    unsigned* pairs = (unsigned*)srcs;  // alias: k_csr stages reads in LDS first

    k_hist_node1<<<NBLK + NODE1_B, 256, 0, stream>>>(ei, hist_g, x, W1, as1w, ad1w,
                                                     h1a, h1b, as1h0, as1h1, ad1h0, ad1h1);
    k_scan1<<<SCAN_B2, 256, 0, stream>>>(hist_g, bsum);
    k_scan3<<<SCAN_B2, 256, 0, stream>>>(hist_g, bsum, hist_s, bbase);
    k_part<<<NBLK, 512, 0, stream>>>(ei, hist_s, pairs);
    k_csr<<<NB, 256, 0, stream>>>(pairs, bbase, offs, srcs);
    k_agg1h<0><<<25000, 256, 0, stream>>>(offs, srcs, as1h0, ad1h0, (const uint2*)h1a,
                                          b1, W2, as2w, ad2w, o1a, hx);
    k_agg1h<1><<<25000, 256, 0, stream>>>(offs, srcs, as1h1, ad1h1, (const uint2*)h1b,
                                          b1, W2, as2w, ad2w, o1a, hx);
    k_agg2<<<6250, 256, 0, stream>>>(offs, srcs, hx, b2, out);
}

// Round 12
// 133.214 us; speedup vs baseline: 1.0912x; 1.0912x over previous
//
#include <hip/hip_runtime.h>
#include <hip/hip_fp16.h>
#include <float.h>

#define NN 100000
#define NE 1600000
#define NB 391        // buckets of 256 nodes (dst >> 8)
#define NBLK 512      // hist/partition blocks
#define CHUNK 3125    // NE / NBLK
#define TOT (NB * NBLK)              // 200192 hist entries
#define SCAN_B2 ((TOT + 255) / 256)  // 782
#define NODE1_B 391   // node1 blocks: 391*256 = 100096 rows
#define MAXB 12288    // LDS-staged bucket capacity (mean 4092, sigma 64 -> safe)

// ---------- edge loading (int32 vs int64, detected per-block) ----------

__device__ __forceinline__ void load_edge(const int* __restrict__ ei, int is64,
                                          int idx, int& s, int& d) {
    if (is64) {
        const long long* e64 = (const long long*)ei;
        s = (int)e64[idx]; d = (int)e64[NE + idx];
    } else {
        s = ei[idx]; d = ei[NE + idx];
    }
}

__device__ __forceinline__ int load_dst(const int* __restrict__ ei, int is64, int idx) {
    if (is64) return (int)((const long long*)ei)[NE + idx];
    return ei[NE + idx];
}

// first 64 words: odd words are all-zero iff int64 (values < 2^31).
__device__ __forceinline__ int detect64(const int* __restrict__ ei, int t, int* s_flag) {
    if (t < 64) {
        unsigned w = ((const unsigned*)ei)[t];
        unsigned long long m = __ballot((t & 1) && w != 0);
        if (t == 0) *s_flag = (m == 0) ? 1 : 0;
    }
    __syncthreads();
    return *s_flag;
}

// ---------- fused: histogram + layer-1 node transform ----------
// blocks [0, NBLK): per-(block,bucket) histogram of dst (LDS counters).
// blocks [NBLK, NBLK+NODE1_B): node1, lane = row, NO LDS:
//   x row streamed per-lane as float4; W rows via wave-uniform loads (s_load);
//   32 fp32 accumulators; writes interleaved fp16 h1 rows (64 B) + ad1 float2.

__global__ __launch_bounds__(256) void k_hist_node1(
    const int* __restrict__ ei, int* __restrict__ hist_g,
    const float* __restrict__ x, const float* __restrict__ W1,
    const float* __restrict__ att_d,
    uint4* __restrict__ h1r, float2* __restrict__ ad1) {
    __shared__ int h[NB];
    __shared__ int s_flag;
    int t = threadIdx.x;
    if (blockIdx.x < NBLK) {
        // ---- histogram ----
        for (int i = t; i < NB; i += 256) h[i] = 0;
        int is64 = detect64(ei, t, &s_flag);   // barrier covers h zeroing
        int base = blockIdx.x * CHUNK;
        for (int k = t; k < CHUNK; k += 256) {
            int d = load_dst(ei, is64, base + k);
            atomicAdd(&h[d >> 8], 1);
        }
        __syncthreads();
        for (int i = t; i < NB; i += 256) hist_g[i * NBLK + blockIdx.x] = h[i];
    } else {
        // ---- node1 ----
        int lane = t & 63;
        int row = (blockIdx.x - NBLK) * 256 + (t & 192) + lane;  // 4 waves x 64 rows
        int r = row < NN ? row : NN - 1;
        const float4* xr = (const float4*)(x + (size_t)r * 128);
        float acc[32];
        #pragma unroll
        for (int j = 0; j < 32; ++j) acc[j] = 0.f;
        for (int k4 = 0; k4 < 32; ++k4) {       // 4 k-values per iter
            float4 a = xr[k4];
            const float* Wr = W1 + k4 * 128;    // wave-uniform -> scalar loads
            #pragma unroll
            for (int c = 0; c < 4; ++c) {
                float xs = c == 0 ? a.x : c == 1 ? a.y : c == 2 ? a.z : a.w;
                #pragma unroll
                for (int j = 0; j < 32; ++j)
                    acc[j] = fmaf(xs, Wr[c * 32 + j], acc[j]);
            }
        }
        // dst-alphas only (att vector wave-uniform -> scalar loads)
        float d0 = 0.f, d1 = 0.f;
        #pragma unroll
        for (int j = 0; j < 16; ++j) {
            d0 = fmaf(acc[j], att_d[j], d0);
            d1 = fmaf(acc[16 + j], att_d[16 + j], d1);
        }
        if (row < NN) {
            unsigned pk[16];
            #pragma unroll
            for (int q = 0; q < 16; ++q) {
                __half2 hv = __floats2half2_rn(acc[2 * q], acc[2 * q + 1]);
                pk[q] = *(unsigned*)&hv;
            }
            h1r[row * 4 + 0] = make_uint4(pk[0], pk[1], pk[2], pk[3]);
            h1r[row * 4 + 1] = make_uint4(pk[4], pk[5], pk[6], pk[7]);
            h1r[row * 4 + 2] = make_uint4(pk[8], pk[9], pk[10], pk[11]);
            h1r[row * 4 + 3] = make_uint4(pk[12], pk[13], pk[14], pk[15]);
            ad1[row] = make_float2(d0, d1);
        }
    }
}

// ---------- scan phase 1: per-block sums of 256-entry hist chunks ----------

__global__ __launch_bounds__(256) void k_scan1(const int* __restrict__ hist_g,
                                               int* __restrict__ bsum) {
    __shared__ int part[4];
    int t = threadIdx.x;
    int i = blockIdx.x * 256 + t;
    int v = (i < TOT) ? hist_g[i] : 0;
    #pragma unroll
    for (int off = 32; off; off >>= 1) v += __shfl_xor(v, off);
    if ((t & 63) == 0) part[t >> 6] = v;
    __syncthreads();
    if (t == 0) bsum[blockIdx.x] = part[0] + part[1] + part[2] + part[3];
}

// ---------- scan phase 2+3 fused ----------

__global__ __launch_bounds__(256) void k_scan3(const int* __restrict__ hist_g,
                                               const int* __restrict__ bsum,
                                               int* __restrict__ hist_s,
                                               int* __restrict__ bbase) {
    __shared__ int red[4];
    __shared__ int s[256];
    int t = threadIdx.x, b = blockIdx.x;
    int partial = 0;
    for (int i = t; i < b; i += 256) partial += bsum[i];   // L2-hot
    #pragma unroll
    for (int off = 32; off; off >>= 1) partial += __shfl_xor(partial, off);
    if ((t & 63) == 0) red[t >> 6] = partial;
    int i = b * 256 + t;
    int v = (i < TOT) ? hist_g[i] : 0;
    s[t] = v;
    __syncthreads();
    int boff = red[0] + red[1] + red[2] + red[3];
    for (int off = 1; off < 256; off <<= 1) {
        int u = (t >= off) ? s[t - off] : 0;
        __syncthreads();
        s[t] += u;
        __syncthreads();
    }
    if (i < TOT) {
        int e = boff + s[t] - v;
        hist_s[i] = e;
        if ((i & (NBLK - 1)) == 0) bbase[i / NBLK] = e;
    }
    if (b == 0 && t == 0) bbase[NB] = NE;
}

// ---------- partition: place packed (src<<8 | dst&255) ----------

__global__ __launch_bounds__(512) void k_part(const int* __restrict__ ei,
                                              const int* __restrict__ hist_s,
                                              unsigned* __restrict__ pairs) {
    __shared__ int cur[NB];
    __shared__ int s_flag;
    int t = threadIdx.x;
    for (int i = t; i < NB; i += 512) cur[i] = hist_s[i * NBLK + blockIdx.x];
    int is64 = detect64(ei, t, &s_flag);
    int base = blockIdx.x * CHUNK;
    for (int k = t; k < CHUNK; k += 512) {
        int s, d; load_edge(ei, is64, base + k, s, d);
        int p = atomicAdd(&cur[d >> 8], 1);
        pairs[p] = ((unsigned)s << 8) | (unsigned)(d & 255);
    }
}

// ---------- per-bucket local CSR build (LDS-staged; srcs aliases pairs) ----------

__global__ __launch_bounds__(256) void k_csr(const unsigned* __restrict__ pairs,
                                             const int* __restrict__ bbase,
                                             int* __restrict__ offs,
                                             int* __restrict__ srcs) {
    __shared__ unsigned plds[MAXB];
    __shared__ int cnt_l[256];
    __shared__ int scan_l[256];
    int b = blockIdx.x, t = threadIdx.x;
    int beg = bbase[b], end = bbase[b + 1];
    int m = end - beg;
    if (m > MAXB) m = MAXB;
    for (int k = t; k < m; k += 256) plds[k] = pairs[beg + k];
    cnt_l[t] = 0;
    __syncthreads();
    for (int k = t; k < m; k += 256) atomicAdd(&cnt_l[plds[k] & 255], 1);
    __syncthreads();
    int v = cnt_l[t];
    scan_l[t] = v;
    __syncthreads();
    for (int off = 1; off < 256; off <<= 1) {
        int u = (t >= off) ? scan_l[t - off] : 0;
        __syncthreads();
        scan_l[t] += u;
        __syncthreads();
    }
    int lexcl = scan_l[t] - v;
    int node = (b << 8) + t;
    if (node < NN) offs[node] = beg + lexcl;
    if (b == 0 && t == 0) offs[NN] = NE;
    cnt_l[t] = lexcl;
    __syncthreads();
    for (int k = t; k < m; k += 256) {
        unsigned e = plds[k];
        int p = atomicAdd(&cnt_l[e & 255], 1);
        srcs[beg + p] = (int)(e >> 8);
    }
}

// ---------- layer 1 aggregate + fused relu + layer-2 transform ----------
// One wave per dst node: 8 edge-groups x 8 lanes x 4 feats (uint2 = 8B of the
// 64B interleaved fp16 row) -> 8 edges per loop iteration. alpha_src computed
// IN-REGISTER from the gathered row (dot4 + 2 shfl), eliminating the separate
// alpha gather stream. ad1 read once per node as float2.

__global__ __launch_bounds__(256) void k_agg1(
    const int* __restrict__ offs, const int* __restrict__ srcs,
    const float2* __restrict__ ad1, const uint2* __restrict__ h1x,
    const float* __restrict__ att_s, const float* __restrict__ b1,
    const float* __restrict__ W2, const float* __restrict__ as2w,
    const float* __restrict__ ad2w, uint2* __restrict__ hx) {
    int n = (blockIdx.x * blockDim.x + threadIdx.x) >> 6;
    if (n >= NN) return;
    int lane = threadIdx.x & 63;
    int eg = lane >> 3;          // edge group 0..7
    int j4 = lane & 7;           // feature quad: feats {4*j4 .. 4*j4+3}
    float4 av = ((const float4*)att_s)[j4];     // att_src quad for my feats
    int beg = offs[n];
    int deg = offs[n + 1] - beg;           // +1 virtual self-loop
    int tot = deg + 1;
    float2 adp = ad1[n];
    float adh = (j4 < 4) ? adp.x : adp.y;
    float ac0 = 0.f, ac1 = 0.f, ac2 = 0.f, ac3 = 0.f, dsum = 0.f;
    int k = eg;
    int s0 = (k < tot) ? ((k < deg) ? srcs[beg + k] : n) : 0;
    uint2 v0 = h1x[s0 * 8 + j4];
    for (; k < tot; k += 8) {
        int kn = k + 8;
        int s1 = (kn < tot) ? ((kn < deg) ? srcs[beg + kn] : n) : 0;
        uint2 v1 = h1x[s1 * 8 + j4];
        float2 fa = __half22float2(*(__half2*)&v0.x);
        float2 fb = __half22float2(*(__half2*)&v0.y);
        // alpha_src for own head: dot4 then sum the 4-lane quad
        float tsum = fa.x * av.x + fa.y * av.y + fb.x * av.z + fb.y * av.w;
        tsum += __shfl_xor(tsum, 1);
        tsum += __shfl_xor(tsum, 2);
        float e = tsum + adh;
        e = fmaxf(e, 0.2f * e);            // leaky_relu
        float p = __expf(e);
        ac0 = fmaf(p, fa.x, ac0);
        ac1 = fmaf(p, fa.y, ac1);
        ac2 = fmaf(p, fb.x, ac2);
        ac3 = fmaf(p, fb.y, ac3);
        if ((j4 & 3) == 0) dsum += p;      // lane j4==0 (head0), j4==4 (head1)
        s0 = s1; v0 = v1;
    }
    // reduce across the 8 edge groups (lane bits 3,4,5)
    #pragma unroll
    for (int off = 8; off <= 32; off <<= 1) {
        ac0 += __shfl_xor(ac0, off);
        ac1 += __shfl_xor(ac1, off);
        ac2 += __shfl_xor(ac2, off);
        ac3 += __shfl_xor(ac3, off);
        dsum += __shfl_xor(dsum, off);
    }
    float denom = __shfl(dsum, j4 & 4);    // lane 0 -> head0, lane 4 -> head1
    float inv = 1.f / (denom + 1e-16f);
    // fused epilogue (all 8 edge groups duplicate, harmless)
    float4 bb = ((const float4*)b1)[j4];
    float r0 = fmaxf(ac0 * inv + bb.x, 0.f);
    float r1 = fmaxf(ac1 * inv + bb.y, 0.f);
    float r2 = fmaxf(ac2 * inv + bb.z, 0.f);
    float r3 = fmaxf(ac3 * inv + bb.w, 0.f);
    float4 wA = ((const float4*)W2)[2 * j4];      // rows 4j4,4j4+1 x cols {0,1}
    float4 wB = ((const float4*)W2)[2 * j4 + 1];  // rows 4j4+2,4j4+3
    float c0 = r0 * wA.x + r1 * wA.z + r2 * wB.x + r3 * wB.z;
    float c1 = r0 * wA.y + r1 * wA.w + r2 * wB.y + r3 * wB.w;
    #pragma unroll
    for (int off = 4; off; off >>= 1) {
        c0 += __shfl_xor(c0, off);
        c1 += __shfl_xor(c1, off);
    }
    if (lane == 0) {
        float a_s = c0 * as2w[0] + c1 * as2w[1];
        float a_d = c0 * ad2w[0] + c1 * ad2w[1];
        __half2 lo = __floats2half2_rn(c0, c1);
        __half2 hi = __floats2half2_rn(a_s, a_d);
        uint2 pk;
        pk.x = *(unsigned*)&lo;
        pk.y = *(unsigned*)&hi;
        hx[n] = pk;
    }
}

// ---------- layer 2 aggregate: 16 lanes per dst node, value-prefetched ----------

__global__ __launch_bounds__(256) void k_agg2(
    const int* __restrict__ offs, const int* __restrict__ srcs,
    const uint2* __restrict__ hx, const float* __restrict__ b2,
    float* __restrict__ out) {
    int n = (blockIdx.x * blockDim.x + threadIdx.x) >> 4;
    if (n >= NN) return;
    int lane = threadIdx.x & 15;
    int beg = offs[n];
    int deg = offs[n + 1] - beg;
    uint2 mynode = hx[n];
    __half2 myhi = *(__half2*)&mynode.y;
    float adv = __high2float(myhi);
    float dsum = 0.f, s0acc = 0.f, s1acc = 0.f;
    int k = lane;
    int s0 = (k <= deg) ? ((k < deg) ? srcs[beg + k] : n) : 0;
    uint2 r0 = hx[s0];
    for (; k <= deg; k += 16) {
        int kn = k + 16;
        int s1 = (kn <= deg) ? ((kn < deg) ? srcs[beg + kn] : n) : 0;
        uint2 r1 = hx[s1];
        __half2 lo = *(__half2*)&r0.x;   // {h2_0, h2_1}
        __half2 hi = *(__half2*)&r0.y;   // {as2, ad2}
        float e = __low2float(hi) + adv;
        e = fmaxf(e, 0.2f * e);
        float p = __expf(e);
        dsum += p;
        s0acc = fmaf(p, __low2float(lo), s0acc);
        s1acc = fmaf(p, __high2float(lo), s1acc);
        r0 = r1;
    }
    #pragma unroll
    for (int off = 8; off; off >>= 1) {
        dsum  += __shfl_xor(dsum, off, 16);
        s0acc += __shfl_xor(s0acc, off, 16);
        s1acc += __shfl_xor(s1acc, off, 16);
    }
    if (lane == 0) {
        float inv = 1.f / (dsum + 1e-16f);
        out[n * 2]     = s0acc * inv + b2[0];
        out[n * 2 + 1] = s1acc * inv + b2[1];
    }
}

// ---------- launch ----------

extern "C" void kernel_launch(void* const* d_in, const int* in_sizes, int n_in,
                              void* d_out, int out_size, void* d_ws, size_t ws_size,
                              hipStream_t stream) {
    const float* x    = (const float*)d_in[0];
    const int*   ei   = (const int*)d_in[1];
    const float* W1   = (const float*)d_in[2];
    const float* as1w = (const float*)d_in[3];
    const float* ad1w = (const float*)d_in[4];
    const float* b1   = (const float*)d_in[5];
    const float* W2   = (const float*)d_in[6];
    const float* as2w = (const float*)d_in[7];
    const float* ad2w = (const float*)d_in[8];
    const float* b2   = (const float*)d_in[9];
    float* out = (float*)d_out;

    float* ws = (float*)d_ws;
    uint4* h1r = (uint4*)ws; ws += 16 * NN;   // 32 fp16/row = 64 B, 6.4 MB
    float2* ad1 = (float2*)ws; ws += 2 * NN;
    uint2* hx  = (uint2*)ws; ws += 2 * NN;
    int* offs   = (int*)ws; ws += NN + 1;
    int* srcs   = (int*)ws; ws += NE;
    int* hist_g = (int*)ws; ws += TOT;
    int* hist_s = (int*)ws; ws += TOT;
    int* bsum   = (int*)ws; ws += SCAN_B2;
    int* bbase  = (int*)ws; ws += NB + 1;
    unsigned* pairs = (unsigned*)srcs;  // alias: k_csr stages reads in LDS first

    k_hist_node1<<<NBLK + NODE1_B, 256, 0, stream>>>(ei, hist_g, x, W1, ad1w, h1r, ad1);
    k_scan1<<<SCAN_B2, 256, 0, stream>>>(hist_g, bsum);
    k_scan3<<<SCAN_B2, 256, 0, stream>>>(hist_g, bsum, hist_s, bbase);
    k_part<<<NBLK, 512, 0, stream>>>(ei, hist_s, pairs);
    k_csr<<<NB, 256, 0, stream>>>(pairs, bbase, offs, srcs);
    k_agg1<<<25000, 256, 0, stream>>>(offs, srcs, ad1, (const uint2*)h1r,
                                      as1w, b1, W2, as2w, ad2w, hx);
    k_agg2<<<6250, 256, 0, stream>>>(offs, srcs, hx, b2, out);
}